// Round 11
// baseline (332.784 us; speedup 1.0000x reference)
//
#include <hip/hip_runtime.h>
#include <cstdint>
#include <cstddef>

typedef __bf16 bf16_t;
typedef __bf16 bf16x8 __attribute__((ext_vector_type(8)));
typedef float  f32x4  __attribute__((ext_vector_type(4)));
typedef unsigned int uint32x4 __attribute__((ext_vector_type(4)));
typedef unsigned int uint32x2 __attribute__((ext_vector_type(2)));

#define DEV_INLINE __device__ __forceinline__

constexpr int Bsz = 4, Ssz = 2048, HID = 1024, FAC = 256, NH = 16, DKc = 64;
constexpr int Mrows = Bsz * Ssz; // 8192
constexpr float QSCALE = 0.18033688011112042f; // (1/sqrt(64)) * log2(e)

struct Ptr8 { const float* p[8]; };
struct Ptr3 { const float* p[3]; };

DEV_INLINE float fast_exp2(float x) {
#if __has_builtin(__builtin_amdgcn_exp2f)
  return __builtin_amdgcn_exp2f(x);
#else
  return exp2f(x);
#endif
}

// async global->LDS, 16 B per lane. LDS dest is wave-uniform base + lane*16.
DEV_INLINE void async16(const void* g, void* l) {
  __builtin_amdgcn_global_load_lds((const __attribute__((address_space(1))) void*)g,
                                   (__attribute__((address_space(3))) void*)l, 16, 0, 0);
}

// Counted-vmcnt barrier: wait until only the N newest VMEM ops remain in flight,
// drain LDS ops, then RAW barrier (no implicit drain).
#define WBAR(N) do { \
  asm volatile("s_waitcnt vmcnt(" #N ") lgkmcnt(0)" ::: "memory"); \
  __builtin_amdgcn_s_barrier(); \
} while (0)

// bank swizzle for [64][64] bf16 tiles staged by global_load_lds (attn).
DEV_INLINE int SW(int r) { return (r & 3) | ((r >> 1) & 4); }
// bank swizzle for [R][32] bf16 tiles (64 B rows): slot s of row r holds logical
// col16 (s ^ SW32(r)); post-swizzle 2-way = free. Invariant under r+16/r+64.
DEV_INLINE int SW32(int r) { return (r >> 1) & 3; }

// ---------------- prep: weight transpose+cast (z<8) + bias/mask pack (z==8) ----------------
__global__ __launch_bounds__(256) void k_prep(Ptr8 w, Ptr8 bsrc, const int* __restrict__ mask,
                                              bf16_t* wpt, bf16_t* wtt,
                                              float* bp, float* bt, float* mf, bf16_t* mb) {
  const int z = blockIdx.z;
  if (z == 8) {
    if (blockIdx.x >= 64) return;
    const int i = blockIdx.x * 256 + threadIdx.x; // 0..16383
    if (i < 4 * FAC) bp[i] = bsrc.p[i >> 8][i & 255];
    if (i < 4 * HID) bt[i] = bsrc.p[4 + (i >> 10)][i & 1023];
    if (i < Bsz * Ssz) {
      const float m = (mask[i] != 0) ? 1.f : 0.f;
      mf[i] = m;
      mb[i] = (bf16_t)m;
    }
    return;
  }
  const int K = (z < 4) ? HID : FAC;
  const int N = (z < 4) ? FAC : HID;
  const int nbN = N / 32;
  const int nb = (blockIdx.x % nbN) * 32, kb = (blockIdx.x / nbN) * 32;
  __shared__ float t[32][33];
  const float* src = w.p[z];
  bf16_t* dst = (z < 4) ? (wpt + (size_t)z * FAC * HID) : (wtt + (size_t)(z - 4) * FAC * HID);
  const int tx = threadIdx.x & 31, ty = threadIdx.x >> 5;
#pragma unroll
  for (int j = 0; j < 4; ++j)
    t[ty + j * 8][tx] = src[(size_t)(kb + ty + j * 8) * N + nb + tx];
  __syncthreads();
#pragma unroll
  for (int j = 0; j < 4; ++j)
    dst[(size_t)(nb + ty + j * 8) * K + kb + tx] = (bf16_t)t[tx][ty + j * 8];
}

// ---------------- fused factored linear v3: OUT[128,1024] = (leaky(A@Wp^T+bp))@Wt^T + bt ----
// R10's correctness bug: async16 rings with issue-before-barrier need R >= D+2 (R6 rule);
// k_fact2 used R=3 with D=2 -> stale-tile race. v3: all async16 rings are RING-4 (&3).
// CAST-A's ds_write-staged As stays ring-3 (write happens AFTER barrier(it) -> 2-barrier
// separation holds). LDS overflow avoided by ALIASING Hl over the phase-1 A region
// (phase-disjoint; barrier before the Hl-write epilogue protects iter-31 As reads).
// LDS: Hl 128x264 (67.6KB, aliases As 15-16KB) + Bs 4x256x32 (64KB) = 133KB -> 1 block/CU.
template <int CAST_A, int QKV, typename OUT_T>
__global__ __launch_bounds__(512, 2) void k_fact2(Ptr3 Asrc, const bf16_t* __restrict__ Abf,
                                                  const bf16_t* __restrict__ WpB,
                                                  const float* __restrict__ bpB,
                                                  const bf16_t* __restrict__ WtB,
                                                  const float* __restrict__ btB,
                                                  OUT_T* __restrict__ CoutAll,
                                                  bf16_t* __restrict__ C2,
                                                  const float* __restrict__ rowmul) {
  constexpr int LDTA = CAST_A ? 40 : 32;
  __shared__ __align__(16) bf16_t smem[128 * 264 + 4 * 256 * 32];
  bf16_t* As = smem;               // phase1 A: CAST 3x128x40 (15360) | o 4x128x32 (16384)
  bf16_t* Hl = smem;               // phase2 A: 128x264 (33792) — aliases As (disjoint phases)
  bf16_t* Bs = smem + 128 * 264;   // weight tiles: 4 bufs x 256x32 (8192 each)

  const int z = QKV ? blockIdx.z : 0;
  const bf16_t* Wp = WpB + (size_t)z * FAC * HID;
  const float* bp = bpB + z * FAC;
  const bf16_t* Wt = WtB + (size_t)z * FAC * HID;
  const float* bt = btB + z * HID;
  OUT_T* Cout = QKV ? (CoutAll + (size_t)z * Mrows * HID) : CoutAll;

  const int tid = threadIdx.x;
  const int lane = tid & 63, wave = tid >> 6; // 0..7
  const int quad = lane >> 4, l16 = lane & 15;
  const int swl = SW32(l16);
  const int m0 = blockIdx.x * 128;

  // weight-tile staging: wave stages rows [wave*32, wave*32+32) of a [256][32] tile.
  const int b1row = wave * 32 + (lane >> 2);
  const int bslot = (((lane & 3) ^ SW32(b1row)) & 3) * 8; // pre-swizzled global col
  const int wOff = wave * 1024;                           // 32 rows x 32 = 1024 elems
  const bf16_t* gW0 = Wp + (size_t)b1row * HID + bslot;
  const bf16_t* gW1 = gW0 + (size_t)16 * HID;

  // A staging
  const int crow = tid >> 2, chalf = (tid & 3) * 8; // cast path: 128 rows x 8 f32/thread
  const float* gAf = nullptr;
  const bf16_t* gAb = nullptr;
  if (CAST_A) {
    gAf = Asrc.p[z] + (size_t)(m0 + crow) * HID + chalf;
  } else {
    const int arowA = wave * 16 + (lane >> 2);
    const int aslot = (((lane & 3) ^ SW32(arowA)) & 3) * 8;
    gAb = Abf + (size_t)(m0 + arowA) * HID + aslot;
  }

#define STB1(t)                                              \
  do {                                                       \
    const int k0_ = (t) * 32;                                \
    bf16_t* d_ = Bs + ((t) & 3) * 8192 + wOff;               \
    async16(gW0 + k0_, d_);                                  \
    async16(gW1 + k0_, d_ + 512);                            \
  } while (0)
#define STA1(t) async16(gAb + (t) * 32, As + ((t) & 3) * 4096 + wave * 512)

  // ---- phase 1 prologue ----
  if (CAST_A) {
    f32x4 pa = *(const f32x4*)gAf;
    f32x4 pb = *(const f32x4*)(gAf + 4);
    __builtin_amdgcn_sched_barrier(0);
    STB1(0);
    STB1(1);
    union { bf16_t h[8]; uint32x4 u; } o;
#pragma unroll
    for (int j = 0; j < 4; ++j) { o.h[j] = (bf16_t)pa[j]; o.h[4 + j] = (bf16_t)pb[j]; }
    *(uint32x4*)(As + crow * LDTA + chalf) = o.u;
  } else {
    STA1(0); STB1(0);
    STA1(1); STB1(1);
  }

  f32x4 acc[8][2] = {};
  constexpr int nk = 32;

  for (int it = 0; it < nk; ++it) {
    if (CAST_A) {
      f32x4 xa, xb;
      const int k1 = (it + 1) * 32;
      if (it + 1 < nk) {
        xa = *(const f32x4*)(gAf + k1);
        xb = *(const f32x4*)(gAf + k1 + 4);
      }
      __builtin_amdgcn_sched_barrier(0);
      if (it + 2 < nk) STB1(it + 2);
      if (it + 2 < nk)      WBAR(6);
      else if (it + 1 < nk) WBAR(4);
      else                  WBAR(0);

      const bf16_t* Ac = As + (it % 3) * (128 * 40);
      const bf16_t* Bc = Bs + (it & 3) * 8192;
      bf16x8 af[8], bfr[2];
#pragma unroll
      for (int i = 0; i < 8; ++i)
        af[i] = *(const bf16x8*)(Ac + (i * 16 + l16) * LDTA + quad * 8);
#pragma unroll
      for (int i = 0; i < 2; ++i)
        bfr[i] = *(const bf16x8*)(Bc + (wave * 32 + i * 16 + l16) * 32 + ((quad ^ swl) & 3) * 8);
#pragma unroll
      for (int mi = 0; mi < 8; ++mi)
#pragma unroll
        for (int ni = 0; ni < 2; ++ni)
          acc[mi][ni] = __builtin_amdgcn_mfma_f32_16x16x32_bf16(af[mi], bfr[ni], acc[mi][ni], 0, 0, 0);

      if (it + 1 < nk) {
        union { bf16_t h[8]; uint32x4 u; } o;
#pragma unroll
        for (int j = 0; j < 4; ++j) { o.h[j] = (bf16_t)xa[j]; o.h[4 + j] = (bf16_t)xb[j]; }
        *(uint32x4*)(As + ((it + 1) % 3) * (128 * 40) + crow * LDTA + chalf) = o.u;
      }
    } else {
      if (it + 2 < nk) { STA1(it + 2); STB1(it + 2); }
      if (it + 2 < nk)      WBAR(6);
      else if (it + 1 < nk) WBAR(3);
      else                  WBAR(0);

      const bf16_t* Ac = As + (it & 3) * 4096;
      const bf16_t* Bc = Bs + (it & 3) * 8192;
      bf16x8 af[8], bfr[2];
#pragma unroll
      for (int i = 0; i < 8; ++i)
        af[i] = *(const bf16x8*)(Ac + (i * 16 + l16) * LDTA + ((quad ^ swl) & 3) * 8);
#pragma unroll
      for (int i = 0; i < 2; ++i)
        bfr[i] = *(const bf16x8*)(Bc + (wave * 32 + i * 16 + l16) * 32 + ((quad ^ swl) & 3) * 8);
#pragma unroll
      for (int mi = 0; mi < 8; ++mi)
#pragma unroll
        for (int ni = 0; ni < 2; ++ni)
          acc[mi][ni] = __builtin_amdgcn_mfma_f32_16x16x32_bf16(af[mi], bfr[ni], acc[mi][ni], 0, 0, 0);
    }
  }
#undef STA1

  // ---- phase 1 epilogue: protect aliased As reads, then bias+leaky -> Hl ----
  __syncthreads(); // iter-31 As/Bs ds_reads complete in ALL waves before Hl overwrite
#pragma unroll
  for (int mi = 0; mi < 8; ++mi)
#pragma unroll
    for (int ni = 0; ni < 2; ++ni) {
      const int col = wave * 32 + ni * 16 + l16;
      const float bv = bp[col];
#pragma unroll
      for (int r = 0; r < 4; ++r) {
        float y = acc[mi][ni][r] + bv;
        y = (y > 0.f) ? y : 0.2f * y;
        Hl[(mi * 16 + quad * 4 + r) * 264 + col] = (bf16_t)y;
      }
      acc[mi][ni] = (f32x4){0.f, 0.f, 0.f, 0.f};
    }
  __syncthreads(); // Hl visible

  // ---- phase 2: OUT = H @ Wt^T + bt, ring-4, D=2, WBAR(4/2/0) ----
#define STG2(ci)                                                              \
  do {                                                                        \
    const int nb_ = ((ci) >> 3) * 256, k0_ = ((ci) & 7) * 32;                 \
    const bf16_t* g_ = Wt + (size_t)(nb_ + b1row) * FAC + k0_ + bslot;        \
    bf16_t* d_ = Bs + ((ci) & 3) * 8192 + wOff;                               \
    async16(g_, d_);                                                          \
    async16(g_ + 16 * FAC, d_ + 512);                                         \
  } while (0)

  STG2(0);
  STG2(1);

  for (int ci = 0; ci < 32; ++ci) {
    if (ci + 2 < 32) STG2(ci + 2);
    if (ci + 2 < 32)      WBAR(4);
    else if (ci + 1 < 32) WBAR(2);
    else                  WBAR(0);

    const bf16_t* Bc = Bs + (ci & 3) * 8192;
    const int k0 = (ci & 7) * 32;
    bf16x8 af[8], bfr[2];
#pragma unroll
    for (int i = 0; i < 8; ++i)
      af[i] = *(const bf16x8*)(Hl + (i * 16 + l16) * 264 + k0 + quad * 8);
#pragma unroll
    for (int i = 0; i < 2; ++i)
      bfr[i] = *(const bf16x8*)(Bc + (wave * 32 + i * 16 + l16) * 32 + ((quad ^ swl) & 3) * 8);
#pragma unroll
    for (int mi = 0; mi < 8; ++mi)
#pragma unroll
      for (int ni = 0; ni < 2; ++ni)
        acc[mi][ni] = __builtin_amdgcn_mfma_f32_16x16x32_bf16(af[mi], bfr[ni], acc[mi][ni], 0, 0, 0);

    if ((ci & 7) == 7) {
      const int nbase = (ci >> 3) * 256;
      if (QKV && z == 2) {
        // v: transposed masked write V^T[(b*NH+h)*64+d][s] = (acc+bt)*mask[s]
#pragma unroll
        for (int mi = 0; mi < 8; ++mi) {
          const int rbase = m0 + mi * 16 + quad * 4;
          const int bb = rbase >> 11, s = rbase & 2047;
          float rmv[4];
#pragma unroll
          for (int r = 0; r < 4; ++r) rmv[r] = rowmul[rbase + r];
#pragma unroll
          for (int ni = 0; ni < 2; ++ni) {
            const int col = nbase + wave * 32 + ni * 16 + l16;
            const float bv = bt[col];
            const int hh = col >> 6, d = col & 63;
            union { bf16_t e[4]; uint32x2 u; } p;
#pragma unroll
            for (int r = 0; r < 4; ++r) p.e[r] = (bf16_t)((acc[mi][ni][r] + bv) * rmv[r]);
            *(uint32x2*)(C2 + (((size_t)((bb * NH + hh) * DKc + d)) << 11) + s) = p.u;
          }
        }
      } else {
        const float scale = (QKV && z == 0) ? QSCALE : 1.f;
#pragma unroll
        for (int mi = 0; mi < 8; ++mi) {
          const int row = m0 + mi * 16 + quad * 4;
#pragma unroll
          for (int ni = 0; ni < 2; ++ni) {
            const int col = nbase + wave * 32 + ni * 16 + l16;
            const float bv = bt[col];
#pragma unroll
            for (int r = 0; r < 4; ++r)
              Cout[(size_t)(row + r) * HID + col] = (OUT_T)((acc[mi][ni][r] + bv) * scale);
          }
        }
      }
#pragma unroll
      for (int mi = 0; mi < 8; ++mi)
#pragma unroll
        for (int ni = 0; ni < 2; ++ni) acc[mi][ni] = (f32x4){0.f, 0.f, 0.f, 0.f};
    }
  }
#undef STG2
#undef STB1
}

// ---------------- flash attention v9 (R5 exact): 512 q-rows/block, 8 waves x 4 q-groups ----------------
__global__ __launch_bounds__(512, 2) void k_attn(const bf16_t* __restrict__ qkv,
                                                 const bf16_t* __restrict__ mb,
                                                 bf16_t* __restrict__ cv) {
  __shared__ __align__(16) bf16_t Ks[4][64 * 64];
  __shared__ __align__(16) bf16_t Vt[4][64 * 64];
  __shared__ __align__(16) bf16_t Ml[Ssz];

  const int qt = blockIdx.x, h = blockIdx.y, b = blockIdx.z;
  const bf16_t* qp = qkv;
  const bf16_t* kp = qkv + (size_t)Mrows * HID;
  const bf16_t* vtp = qkv + 2 * (size_t)Mrows * HID + (size_t)(b * NH + h) * DKc * Ssz;

  const int tid = threadIdx.x;
  const int lane = tid & 63, wave = tid >> 6;
  const int quad = lane >> 4, l16 = lane & 15;

  const int r0 = wave * 8 + (lane >> 3);
  const int c0 = ((lane & 7) ^ SW(r0)) * 8;
  const int ldsOff = wave * 512;
  const bf16_t* kgA = kp + (size_t)(b * Ssz + r0) * HID + h * DKc + c0;
  const bf16_t* vgA = vtp + (size_t)r0 * Ssz + c0;

#define STAGEA(t, buf)                                          \
  do {                                                          \
    async16(kgA + (size_t)(t) * 64 * HID, Ks[buf] + ldsOff);    \
    async16(vgA + (t) * 64, Vt[buf] + ldsOff);                  \
  } while (0)

  *(uint32x2*)(Ml + tid * 4) = *(const uint32x2*)(mb + (size_t)b * Ssz + tid * 4);
  STAGEA(0, 0);
  STAGEA(1, 1);

  bf16x8 aq0[4], aq1[4];
#pragma unroll
  for (int g = 0; g < 4; ++g) {
    const size_t qrow = (size_t)(b * Ssz + qt * 512 + g * 128 + wave * 16 + l16) * HID + h * DKc + quad * 8;
    aq0[g] = *(const bf16x8*)(qp + qrow);
    aq1[g] = *(const bf16x8*)(qp + qrow + 32);
  }

  const int krow = 8 * (l16 >> 2) + (l16 & 3);
  f32x4 acc[4][4] = {};
  f32x4 dacc[4] = {};
  const bf16x8 zfrag = {};

  for (int kt = 0; kt < 32; ++kt) {
    if (kt + 2 < 32) STAGEA(kt + 2, (kt + 2) & 3);

    if (kt + 2 < 32)      WBAR(4);
    else if (kt + 1 < 32) WBAR(2);
    else                  WBAR(0);

    const bf16_t* Kc = Ks[kt & 3];
    const bf16_t* Vc = Vt[kt & 3];

    union U { uint32x4 u; bf16x8 h; } ap0[4], ap1[4];
    constexpr int koff[4] = {0, 4, 32, 36};
#pragma unroll
    for (int ks = 0; ks < 4; ++ks) {
      const int row = krow + koff[ks];
      const int sw = SW(row);
      bf16x8 a0 = *(const bf16x8*)(Kc + row * 64 + (quad ^ sw) * 8);
      bf16x8 a1 = *(const bf16x8*)(Kc + row * 64 + ((quad + 4) ^ sw) * 8);
#pragma unroll
      for (int g = 0; g < 4; ++g) {
        f32x4 c = {};
        c = __builtin_amdgcn_mfma_f32_16x16x32_bf16(a0, aq0[g], c, 0, 0, 0);
        c = __builtin_amdgcn_mfma_f32_16x16x32_bf16(a1, aq1[g], c, 0, 0, 0);
        union { bf16_t h[2]; uint32_t u; } p01, p23;
        p01.h[0] = (bf16_t)fast_exp2(c[0]);
        p01.h[1] = (bf16_t)fast_exp2(c[1]);
        p23.h[0] = (bf16_t)fast_exp2(c[2]);
        p23.h[1] = (bf16_t)fast_exp2(c[3]);
        U& t = (ks < 2) ? ap0[g] : ap1[g];
        t.u[(ks & 1) * 2] = p01.u;
        t.u[(ks & 1) * 2 + 1] = p23.u;
      }
    }

    bf16x8 mr0 = *(const bf16x8*)(Ml + kt * 64 + quad * 8);
    bf16x8 mr1 = *(const bf16x8*)(Ml + kt * 64 + 32 + quad * 8);
    if (l16 != 0) { mr0 = zfrag; mr1 = zfrag; }
#pragma unroll
    for (int g = 0; g < 4; ++g) {
      dacc[g] = __builtin_amdgcn_mfma_f32_16x16x32_bf16(ap0[g].h, mr0, dacc[g], 0, 0, 0);
      dacc[g] = __builtin_amdgcn_mfma_f32_16x16x32_bf16(ap1[g].h, mr1, dacc[g], 0, 0, 0);
    }

#pragma unroll
    for (int d = 0; d < 4; ++d) {
      const int row = d * 16 + l16;
      const int sw = SW(row);
      bf16x8 bv0 = *(const bf16x8*)(Vc + row * 64 + (quad ^ sw) * 8);
      bf16x8 bv1 = *(const bf16x8*)(Vc + row * 64 + ((quad + 4) ^ sw) * 8);
#pragma unroll
      for (int g = 0; g < 4; ++g) {
        acc[g][d] = __builtin_amdgcn_mfma_f32_16x16x32_bf16(ap0[g].h, bv0, acc[g][d], 0, 0, 0);
        acc[g][d] = __builtin_amdgcn_mfma_f32_16x16x32_bf16(ap1[g].h, bv1, acc[g][d], 0, 0, 0);
      }
    }
  }
#undef STAGEA

#pragma unroll
  for (int g = 0; g < 4; ++g) {
    const size_t obase = (size_t)(b * Ssz + qt * 512 + g * 128 + wave * 16 + quad * 4) * HID + h * DKc + l16;
#pragma unroll
    for (int r = 0; r < 4; ++r) {
      const float denom = __shfl(dacc[g][r], lane & 48, 64);
      const float rl = 1.f / denom;
#pragma unroll
      for (int d = 0; d < 4; ++d)
        cv[obase + (size_t)r * HID + d * 16] = (bf16_t)(acc[g][d][r] * rl);
    }
  }
}

// ---------------- host ----------------
extern "C" void kernel_launch(void* const* d_in, const int* in_sizes, int n_in,
                              void* d_out, int out_size, void* d_ws, size_t ws_size,
                              hipStream_t stream) {
  (void)in_sizes; (void)n_in; (void)out_size; (void)ws_size;
  const float* q_in = (const float*)d_in[0];
  const float* k_in = (const float*)d_in[1];
  const float* v_in = (const float*)d_in[2];
  const int* mask = (const int*)d_in[3];

  bf16_t* XB = (bf16_t*)d_ws;                          // 3 slots [8192,1024] bf16: q, k, V^T
  bf16_t* H3 = XB + (size_t)3 * Mrows * HID;           // (unused by fused path)
  bf16_t* CV = H3 + (size_t)3 * Mrows * FAC;           // [8192,1024] bf16 (attn out)
  bf16_t* WPT = CV + (size_t)Mrows * HID;              // 4 x [256,1024] bf16
  bf16_t* WTT = WPT + (size_t)4 * FAC * HID;           // 4 x [1024,256] bf16
  float* BP = (float*)(WTT + (size_t)4 * FAC * HID);   // 4 x 256 f32
  float* BT = BP + 4 * FAC;                            // 4 x 1024 f32
  float* MF = BT + 4 * HID;                            // [8192] f32 mask rowmul
  bf16_t* MB = (bf16_t*)(MF + Mrows);                  // [8192] bf16 mask row
  bf16_t* VTg = XB + 2 * (size_t)Mrows * HID;          // V^T slot

  Ptr8 w;
  w.p[0] = (const float*)d_in[4];  w.p[1] = (const float*)d_in[8];
  w.p[2] = (const float*)d_in[12]; w.p[3] = (const float*)d_in[16];
  w.p[4] = (const float*)d_in[6];  w.p[5] = (const float*)d_in[10];
  w.p[6] = (const float*)d_in[14]; w.p[7] = (const float*)d_in[18];
  Ptr8 bs;
  bs.p[0] = (const float*)d_in[5];  bs.p[1] = (const float*)d_in[9];
  bs.p[2] = (const float*)d_in[13]; bs.p[3] = (const float*)d_in[17];
  bs.p[4] = (const float*)d_in[7];  bs.p[5] = (const float*)d_in[11];
  bs.p[6] = (const float*)d_in[15]; bs.p[7] = (const float*)d_in[19];
  hipLaunchKernelGGL(k_prep, dim3(256, 1, 9), dim3(256), 0, stream, w, bs, mask,
                     WPT, WTT, BP, BT, MF, MB);

  Ptr3 xs; xs.p[0] = q_in; xs.p[1] = k_in; xs.p[2] = v_in;
  Ptr3 nullp; nullp.p[0] = nullp.p[1] = nullp.p[2] = nullptr;

  // fused proj->tran qkv: q (scaled), k -> XB; v masked+TRANSPOSED -> VTg. 192 blocks.
  hipLaunchKernelGGL((k_fact2<1, 1, bf16_t>), dim3(Mrows / 128, 1, 3), dim3(512), 0, stream,
                     xs, (const bf16_t*)nullptr, WPT, BP, WTT, BT, XB, VTg, MF);

  // attention -> CV (512 q-rows per block, 8 waves x 4 groups, 256 blocks)
  hipLaunchKernelGGL(k_attn, dim3(Ssz / 512, NH, Bsz), dim3(512), 0, stream, XB, MB, CV);

  // fused proj->tran o: CV -> d_out (fp32). 64 blocks.
  hipLaunchKernelGGL((k_fact2<0, 0, float>), dim3(Mrows / 128, 1, 1), dim3(512), 0, stream,
                     nullp, CV, WPT + (size_t)3 * FAC * HID, BP + 3 * FAC,
                     WTT + (size_t)3 * FAC * HID, BT + 3 * HID,
                     (float*)d_out, (bf16_t*)nullptr, (const float*)nullptr);
}